// Round 7
// baseline (238.139 us; speedup 1.0000x reference)
//
#include <hip/hip_runtime.h>
#include <hip/hip_bf16.h>
#include <math.h>

typedef __hip_bfloat16 bf16;

// ---------------- problem constants ----------------
#define LSEQ 4096
#define DI 128
#define NSTATE 16
#define NK 4
#define NCHUNK 128
#define CLEN 32
#define CHTOT 16384   // 2 scans * 4 k * 128 d * 16 n

// ---------------- fp32 input staging (packed, converted once per call) ----------------
#define IN_X0    0
#define IN_X1    262144
#define IN_IPW0  524288
#define IN_IPW1  540672
#define IN_CW0   557056
#define IN_CB0   558208
#define IN_CW1   558336
#define IN_CB1   559488
#define IN_XPW0  559616
#define IN_DTW0  578048
#define IN_DTW1  580096
#define IN_DTB0  582144
#define IN_DTB1  582656
#define IN_AL0   583168
#define IN_AL1   591360
#define IN_DS0   599552
#define IN_DS1   600064
#define IN_G0    600576
#define IN_B0    600704
#define IN_G1    600832
#define IN_B1    600960
#define IN_WO0   601088
#define IN_WO1   609280
#define END_IN   617472

// ---------------- intermediate buffers ----------------
#define OFF_XC0  END_IN                     // conv out branch0, [d][l] (row-major pixels)
#define OFF_XC1  (OFF_XC0 + DI*LSEQ)
#define OFF_XT0  (OFF_XC1 + DI*LSEQ)        // transposed plane, [d][w*64+h]
#define OFF_XT1  (OFF_XT0 + DI*LSEQ)
#define OFF_SZ0  (OFF_XT1 + DI*LSEQ)        // silu(z), [l][d]
#define OFF_SZ1  (OFF_SZ0 + LSEQ*DI)
#define OFF_XDBL (OFF_SZ1 + LSEQ*DI)        // [k][36][l]: rows 0-3 dtr, 4-19 B, 20-35 C
#define OFF_CHP  (OFF_XDBL + NK*36*LSEQ)    // [chunk][chain]; after k_comb holds h-init
#define OFF_CHS  (OFF_CHP + NCHUNK*CHTOT)
#define OFF_OY   (OFF_CHS + NCHUNK*CHTOT)   // per-direction scan out, [s][k][l][d]
#define WS_FLOATS (OFF_OY + 2*NK*LSEQ*DI)

__device__ __forceinline__ float softplus_f(float x) {
  return x > 20.f ? x : __logf(1.f + __expf(x));
}
__device__ __forceinline__ float silu_f(float x) {
  return x / (1.f + __expf(-x));
}
// inline dtype probe: wave 0 samples even bf16 indices of in_proj0_w.
// fp32-backed buffer -> even bf16 halves have random exponents -> many |v|>4/NaN.
__device__ __forceinline__ int probe_f32(const void* probe, int t, int* sh) {
  if (t < 64) {
    int idx = 2 * ((t * 127) & 4095);
    float v = __bfloat162float(((const bf16*)probe)[idx]);
    int weird = (!(v == v)) || (fabsf(v) > 4.0f);
    unsigned long long m = __ballot(weird);
    if (t == 0) *sh = (__popcll(m) >= 8) ? 1 : 0;
  }
  __syncthreads();
  return *sh;
}

// ---------------- K0: convert inputs to fp32 staging ----------------
struct Ptrs { const void* p[23]; };
__constant__ const int g_cnt[23] = {262144, 262144, 16384, 16384, 1152, 128, 1152, 128,
                                    18432, 2048, 2048, 512, 512, 8192, 8192, 512, 512,
                                    128, 128, 128, 128, 8192, 8192};
__constant__ const int g_dst[23] = {IN_X0, IN_X1, IN_IPW0, IN_IPW1, IN_CW0, IN_CB0,
                                    IN_CW1, IN_CB1, IN_XPW0, IN_DTW0, IN_DTW1, IN_DTB0,
                                    IN_DTB1, IN_AL0, IN_AL1, IN_DS0, IN_DS1, IN_G0,
                                    IN_B0, IN_G1, IN_B1, IN_WO0, IN_WO1};
__global__ __launch_bounds__(256) void k_convert(Ptrs pt, const void* probe,
                                                 float* __restrict__ ws) {
  __shared__ int sf32;
  int t = threadIdx.x;
  int f32 = probe_f32(probe, t, &sf32);
  int gid = blockIdx.x * 256 + t;
  if (gid < END_IN) {
    int j = 0;
#pragma unroll
    for (int q = 0; q < 22; q++)
      if (gid >= g_dst[q] + g_cnt[q]) j = q + 1;
    int off = gid - g_dst[j];
    float v;
    if (f32) v = ((const float*)pt.p[j])[off];
    else v = __bfloat162float(((const bf16*)pt.p[j])[off]);
    ws[gid] = v;
  }
}

// ---------------- K1: in_proj (x @ W^T), split xi / silu(z) ----------------
__global__ __launch_bounds__(256) void k_inproj(float* __restrict__ ws) {
  int b = blockIdx.y;
  const float* x = ws + (b ? IN_X1 : IN_X0);
  const float* w = ws + (b ? IN_IPW1 : IN_IPW0);
  float* xi = ws + (b ? OFF_XC1 : OFF_XC0);
  float* sz = ws + (b ? OFF_SZ1 : OFF_SZ0);
  int l0 = blockIdx.x * 16;
  int t = threadIdx.x;
  __shared__ float xs_[16][64];
  for (int i = t; i < 1024; i += 256) xs_[i >> 6][i & 63] = x[l0 * 64 + i];
  __syncthreads();
  int j = t;  // output channel 0..255
  float wr[64];
#pragma unroll
  for (int c = 0; c < 64; c++) wr[c] = w[j * 64 + c];
  float acc[16];
#pragma unroll
  for (int p = 0; p < 16; p++) {
    float a = 0.f;
#pragma unroll
    for (int c = 0; c < 64; c++) a += xs_[p][c] * wr[c];
    acc[p] = a;
  }
  if (j < 128) {
#pragma unroll
    for (int p = 0; p < 16; p++) xi[j * LSEQ + l0 + p] = acc[p];
  } else {
    int d = j - 128;
#pragma unroll
    for (int p = 0; p < 16; p++) sz[(l0 + p) * 128 + d] = silu_f(acc[p]);
  }
}

// ---------------- K2: depthwise 3x3 conv + bias + SiLU; emit xc and transposed xcT ----------------
__global__ __launch_bounds__(256) void k_conv(float* __restrict__ ws) {
  int b = blockIdx.y;
  int d = blockIdx.x;
  const float* cw = ws + (b ? IN_CW1 : IN_CW0) + d * 9;
  float bias = (ws + (b ? IN_CB1 : IN_CB0))[d];
  float* xp = ws + (b ? OFF_XC1 : OFF_XC0) + d * LSEQ;
  float* xt = ws + (b ? OFF_XT1 : OFF_XT0) + d * LSEQ;
  float wreg[9];
#pragma unroll
  for (int i = 0; i < 9; i++) wreg[i] = cw[i];
  __shared__ float pl[64][64];
  __shared__ float po[64][65];
  for (int i = threadIdx.x; i < 4096; i += 256) pl[i >> 6][i & 63] = xp[i];
  __syncthreads();
  for (int i = threadIdx.x; i < 4096; i += 256) {
    int h = i >> 6, w = i & 63;
    float a = bias;
#pragma unroll
    for (int kh = 0; kh < 3; kh++) {
      int hh = h + kh - 1;
      if (hh < 0 || hh > 63) continue;
#pragma unroll
      for (int kw = 0; kw < 3; kw++) {
        int ww = w + kw - 1;
        if (ww < 0 || ww > 63) continue;
        a += pl[hh][ww] * wreg[kh * 3 + kw];
      }
    }
    float r = silu_f(a);
    xp[i] = r;
    po[w][h] = r;  // transposed stash
  }
  __syncthreads();
  for (int i = threadIdx.x; i < 4096; i += 256) xt[i] = po[i >> 6][i & 63];
}

// ---------------- K3: x_dbl[k,c,l] = sum_d xs0[k,d,l] * W0[k,c,d] ----------------
__global__ __launch_bounds__(256) void k_xdbl(float* __restrict__ ws) {
  int k = blockIdx.y;
  int l0 = blockIdx.x * 64;
  int t = threadIdx.x;
  __shared__ float xtile[128][64];
  __shared__ float wl[36][128];
  const float* pk = ws + ((k & 1) ? OFF_XT0 : OFF_XC0);  // branch0 planes
  int rev = (k >= 2);
  const float* xpw = ws + IN_XPW0;
  for (int i = t; i < 128 * 64; i += 256) {
    int d = i >> 6, ll = i & 63;
    int idx = rev ? (4095 - (l0 + ll)) : (l0 + ll);
    xtile[d][ll] = pk[d * LSEQ + idx];
  }
  for (int i = t; i < 36 * 128; i += 256) wl[i >> 7][i & 127] = xpw[k * 4608 + i];
  __syncthreads();
  int lane = t & 63;
  int grp = t >> 6;  // 0..3
  float acc[9];
#pragma unroll
  for (int i = 0; i < 9; i++) acc[i] = 0.f;
  for (int d = 0; d < 128; d++) {
    float xv = xtile[d][lane];
#pragma unroll
    for (int i = 0; i < 9; i++) acc[i] += xv * wl[grp + i * 4][d];
  }
  float* xd = ws + OFF_XDBL + k * 36 * LSEQ;
#pragma unroll
  for (int i = 0; i < 9; i++) xd[(grp + i * 4) * LSEQ + l0 + lane] = acc[i];
}

// ---------------- scan kernels ----------------
// thread owns a (s,k,d) chain with 16 n-states in registers.
// cross-wiring: s=0 scans xs0 with dt1/A1/D1 params; s=1 scans xs1 with dt0/A0/D0.
// Fast path: A_logs = log(1..16) => A[n] = (n+1)*A[0]  =>  exp(de*A[n]) = e1^(n+1).

// ---------------- K4a: scan pass 1 — per-chunk (P, S) ----------------
__global__ __launch_bounds__(128, 2) void k_scanA(float* __restrict__ ws) {
  int s = blockIdx.z, k = blockIdx.y, c = blockIdx.x;
  int d = threadIdx.x;  // 0..127
  const float* xd_dt = ws + OFF_XDBL + k * 36 * LSEQ;
  const float* Bb = ws + OFF_XDBL + (k * 36 + 4) * LSEQ;
  const float* alog = ws + (s ? IN_AL0 : IN_AL1);
  const float* dtw = ws + (s ? IN_DTW0 : IN_DTW1);
  const float* dtb = ws + (s ? IN_DTB0 : IN_DTB1);
  const float* uplane = ws + ((s ? OFF_XC1 : OFF_XC0) + ((k & 1) ? 2 * DI * LSEQ : 0)) + d * LSEQ;
  int rev = (k >= 2);
  float A[NSTATE];
#pragma unroll
  for (int n = 0; n < NSTATE; n++) A[n] = -__expf(alog[(k * DI + d) * NSTATE + n]);
  bool fast = true;
#pragma unroll
  for (int n = 1; n < NSTATE; n++)
    fast = fast && (fabsf(A[n] - (float)(n + 1) * A[0]) <= 1e-3f * fabsf(A[n]));
  float4 wrv = *(const float4*)&dtw[(k * DI + d) * 4];
  float dbias = dtb[k * DI + d];
  float h[NSTATE];
#pragma unroll
  for (int n = 0; n < NSTATE; n++) h[n] = 0.f;
  float sde = 0.f;
  __shared__ float dtr_s[4][16];
  __shared__ __align__(16) float Bt[16 * 20];  // row stride 20: conflict-light, 16B-aligned
  int l0 = c * CLEN;
  for (int tile = 0; tile < CLEN / 16; tile++) {
    int l0t = l0 + tile * 16;
    __syncthreads();
    if (d < 64) dtr_s[d >> 4][d & 15] = xd_dt[(d >> 4) * LSEQ + l0t + (d & 15)];
#pragma unroll
    for (int q = 0; q < 2; q++) {
      int i = d + q * 128;
      int n = i >> 4, j = i & 15;
      Bt[j * 20 + n] = Bb[n * LSEQ + l0t + j];
    }
    __syncthreads();
    float de[16];
#pragma unroll
    for (int j = 0; j < 16; j++) {
      de[j] = softplus_f(dtr_s[0][j] * wrv.x + dtr_s[1][j] * wrv.y +
                         dtr_s[2][j] * wrv.z + dtr_s[3][j] * wrv.w + dbias);
      sde += de[j];
    }
    int boff = rev ? (4080 - l0t) : l0t;
    float4 q0 = *(const float4*)&uplane[boff];
    float4 q1 = *(const float4*)&uplane[boff + 4];
    float4 q2 = *(const float4*)&uplane[boff + 8];
    float4 q3 = *(const float4*)&uplane[boff + 12];
    float uu[16] = {q0.x, q0.y, q0.z, q0.w, q1.x, q1.y, q1.z, q1.w,
                    q2.x, q2.y, q2.z, q2.w, q3.x, q3.y, q3.z, q3.w};
#pragma unroll
    for (int j = 0; j < 16; j++) {
      float u = rev ? uu[15 - j] : uu[j];
      float duj = de[j] * u;
      float4 b0 = *(const float4*)&Bt[j * 20 + 0];
      float4 b1 = *(const float4*)&Bt[j * 20 + 4];
      float4 b2 = *(const float4*)&Bt[j * 20 + 8];
      float4 b3 = *(const float4*)&Bt[j * 20 + 12];
      float bv[16] = {b0.x, b0.y, b0.z, b0.w, b1.x, b1.y, b1.z, b1.w,
                      b2.x, b2.y, b2.z, b2.w, b3.x, b3.y, b3.z, b3.w};
      if (fast) {
        float e1 = __expf(de[j] * A[0]);
        float p = e1;
#pragma unroll
        for (int n = 0; n < NSTATE; n++) {
          h[n] = p * h[n] + duj * bv[n];
          p *= e1;
        }
      } else {
#pragma unroll
        for (int n = 0; n < NSTATE; n++) {
          float da = __expf(de[j] * A[n]);
          h[n] = da * h[n] + duj * bv[n];
        }
      }
    }
  }
  int chainb = ((s * 4 + k) * DI + d) * NSTATE;
  float* Pp = ws + OFF_CHP + c * CHTOT + chainb;
  float* Sp = ws + OFF_CHS + c * CHTOT + chainb;
  float4 pv[4], sv[4];
#pragma unroll
  for (int q = 0; q < 4; q++) {
    pv[q] = make_float4(__expf(A[4 * q] * sde), __expf(A[4 * q + 1] * sde),
                        __expf(A[4 * q + 2] * sde), __expf(A[4 * q + 3] * sde));
    sv[q] = make_float4(h[4 * q], h[4 * q + 1], h[4 * q + 2], h[4 * q + 3]);
    ((float4*)Pp)[q] = pv[q];
    ((float4*)Sp)[q] = sv[q];
  }
}

// ---------------- K4b: combine chunk summaries; CHP becomes h-init in place ----------------
__global__ __launch_bounds__(256) void k_comb(float* __restrict__ ws) {
  int chain = blockIdx.x * 256 + threadIdx.x;
  float* P = ws + OFF_CHP + chain;
  float* S = ws + OFF_CHS + chain;
  float h = 0.f;
  for (int g = 0; g < NCHUNK; g += 8) {
    float p[8], sv[8];
#pragma unroll
    for (int i = 0; i < 8; i++) {
      p[i] = P[(g + i) * CHTOT];
      sv[i] = S[(g + i) * CHTOT];
    }
#pragma unroll
    for (int i = 0; i < 8; i++) {
      P[(g + i) * CHTOT] = h;
      h = p[i] * h + sv[i];
    }
  }
}

// ---------------- K4c: scan pass 2 — recompute with init, store y+u*D per direction ----------------
__global__ __launch_bounds__(128, 2) void k_scanB(float* __restrict__ ws) {
  int s = blockIdx.z, k = blockIdx.y, c = blockIdx.x;
  int d = threadIdx.x;
  const float* xd_dt = ws + OFF_XDBL + k * 36 * LSEQ;
  const float* Bb = ws + OFF_XDBL + (k * 36 + 4) * LSEQ;
  const float* Cb = ws + OFF_XDBL + (k * 36 + 20) * LSEQ;
  const float* alog = ws + (s ? IN_AL0 : IN_AL1);
  const float* dtw = ws + (s ? IN_DTW0 : IN_DTW1);
  const float* dtb = ws + (s ? IN_DTB0 : IN_DTB1);
  const float* Dvec = ws + (s ? IN_DS0 : IN_DS1);
  const float* uplane = ws + ((s ? OFF_XC1 : OFF_XC0) + ((k & 1) ? 2 * DI * LSEQ : 0)) + d * LSEQ;
  float* oyb = ws + OFF_OY + (s * NK + k) * (LSEQ * DI);
  int rev = (k >= 2);
  float A[NSTATE];
#pragma unroll
  for (int n = 0; n < NSTATE; n++) A[n] = -__expf(alog[(k * DI + d) * NSTATE + n]);
  bool fast = true;
#pragma unroll
  for (int n = 1; n < NSTATE; n++)
    fast = fast && (fabsf(A[n] - (float)(n + 1) * A[0]) <= 1e-3f * fabsf(A[n]));
  float4 wrv = *(const float4*)&dtw[(k * DI + d) * 4];
  float dbias = dtb[k * DI + d];
  float Dv = Dvec[k * DI + d];
  int chainb = ((s * 4 + k) * DI + d) * NSTATE;
  const float* Hp = ws + OFF_CHP + c * CHTOT + chainb;
  float h[NSTATE];
#pragma unroll
  for (int q = 0; q < 4; q++) {
    float4 hv = ((const float4*)Hp)[q];
    h[4 * q] = hv.x; h[4 * q + 1] = hv.y; h[4 * q + 2] = hv.z; h[4 * q + 3] = hv.w;
  }
  __shared__ float dtr_s[4][16];
  __shared__ __align__(16) float Bt[16 * 20];
  __shared__ __align__(16) float Ct[16 * 20];
  int l0 = c * CLEN;
  for (int tile = 0; tile < CLEN / 16; tile++) {
    int l0t = l0 + tile * 16;
    __syncthreads();
    if (d < 64) dtr_s[d >> 4][d & 15] = xd_dt[(d >> 4) * LSEQ + l0t + (d & 15)];
#pragma unroll
    for (int q = 0; q < 2; q++) {
      int i = d + q * 128;
      int n = i >> 4, j = i & 15;
      Bt[j * 20 + n] = Bb[n * LSEQ + l0t + j];
      Ct[j * 20 + n] = Cb[n * LSEQ + l0t + j];
    }
    __syncthreads();
    float de[16];
#pragma unroll
    for (int j = 0; j < 16; j++) {
      de[j] = softplus_f(dtr_s[0][j] * wrv.x + dtr_s[1][j] * wrv.y +
                         dtr_s[2][j] * wrv.z + dtr_s[3][j] * wrv.w + dbias);
    }
    int boff = rev ? (4080 - l0t) : l0t;
    float4 q0 = *(const float4*)&uplane[boff];
    float4 q1 = *(const float4*)&uplane[boff + 4];
    float4 q2 = *(const float4*)&uplane[boff + 8];
    float4 q3 = *(const float4*)&uplane[boff + 12];
    float uu[16] = {q0.x, q0.y, q0.z, q0.w, q1.x, q1.y, q1.z, q1.w,
                    q2.x, q2.y, q2.z, q2.w, q3.x, q3.y, q3.z, q3.w};
#pragma unroll
    for (int j = 0; j < 16; j++) {
      float u = rev ? uu[15 - j] : uu[j];
      float duj = de[j] * u;
      float4 b0 = *(const float4*)&Bt[j * 20 + 0];
      float4 b1 = *(const float4*)&Bt[j * 20 + 4];
      float4 b2 = *(const float4*)&Bt[j * 20 + 8];
      float4 b3 = *(const float4*)&Bt[j * 20 + 12];
      float bv[16] = {b0.x, b0.y, b0.z, b0.w, b1.x, b1.y, b1.z, b1.w,
                      b2.x, b2.y, b2.z, b2.w, b3.x, b3.y, b3.z, b3.w};
      float4 c0 = *(const float4*)&Ct[j * 20 + 0];
      float4 c1 = *(const float4*)&Ct[j * 20 + 4];
      float4 c2 = *(const float4*)&Ct[j * 20 + 8];
      float4 c3 = *(const float4*)&Ct[j * 20 + 12];
      float cv[16] = {c0.x, c0.y, c0.z, c0.w, c1.x, c1.y, c1.z, c1.w,
                      c2.x, c2.y, c2.z, c2.w, c3.x, c3.y, c3.z, c3.w};
      float y = 0.f;
      if (fast) {
        float e1 = __expf(de[j] * A[0]);
        float p = e1;
#pragma unroll
        for (int n = 0; n < NSTATE; n++) {
          h[n] = p * h[n] + duj * bv[n];
          y += h[n] * cv[n];
          p *= e1;
        }
      } else {
#pragma unroll
        for (int n = 0; n < NSTATE; n++) {
          float da = __expf(de[j] * A[n]);
          h[n] = da * h[n] + duj * bv[n];
          y += h[n] * cv[n];
        }
      }
      y += u * Dv;
      oyb[(l0t + j) * DI + d] = y;  // coalesced store, no atomics
    }
  }
}

// ---------------- K5: 4-dir gather + LayerNorm + silu(z) gate + out_proj ----------------
__global__ __launch_bounds__(256) void k_post(const float* __restrict__ ws,
                                              const void* probe,
                                              void* __restrict__ out) {
  int b = blockIdx.y;
  __shared__ int sf32;
  int t = threadIdx.x;
  int in_f32 = probe_f32(probe, t, &sf32);
  const float* oy = ws + OFF_OY + b * (NK * LSEQ * DI);
  const float* sz = ws + (b ? OFF_SZ1 : OFF_SZ0);
  const float* g = ws + (b ? IN_G1 : IN_G0);
  const float* be = ws + (b ? IN_B1 : IN_B0);
  const float* wo = ws + (b ? IN_WO1 : IN_WO0);
  __shared__ float wl[64][129];
  for (int i = t; i < 8192; i += 256) wl[i >> 7][i & 127] = wo[i];
  __shared__ float yl[2][128];
  __shared__ float red[2][2][2];
  int l0 = blockIdx.x * 32;
  for (int pp = 0; pp < 32; pp += 2) {
    int p2 = t >> 7, d = t & 127;
    int l = l0 + pp + p2;
    int lt = ((l & 63) << 6) | (l >> 6);  // transposed pixel index
    float v = oy[(0 * LSEQ + l) * DI + d] + oy[(1 * LSEQ + lt) * DI + d] +
              oy[(2 * LSEQ + (4095 - l)) * DI + d] + oy[(3 * LSEQ + (4095 - lt)) * DI + d];
    float s1 = v, s2 = v * v;
#pragma unroll
    for (int m = 1; m < 64; m <<= 1) {
      s1 += __shfl_xor(s1, m);
      s2 += __shfl_xor(s2, m);
    }
    __syncthreads();
    if ((t & 63) == 0) {
      red[p2][(t >> 6) & 1][0] = s1;
      red[p2][(t >> 6) & 1][1] = s2;
    }
    __syncthreads();
    float sum = red[p2][0][0] + red[p2][1][0];
    float ssq = red[p2][0][1] + red[p2][1][1];
    float mean = sum * (1.f / 128.f);
    float var = ssq * (1.f / 128.f) - mean * mean;
    float inv = rsqrtf(var + 1e-5f);
    float ya = (v - mean) * inv * g[d] + be[d];
    ya *= sz[l * 128 + d];
    yl[p2][d] = ya;
    __syncthreads();
    if (t < 128) {
      int p2o = t >> 6, m = t & 63;
      int lo = l0 + pp + p2o;
      float a = 0.f;
#pragma unroll 4
      for (int d2 = 0; d2 < 128; d2++) a += yl[p2o][d2] * wl[m][d2];
      int oi = b * (LSEQ * 64) + lo * 64 + m;
      if (in_f32) ((float*)out)[oi] = a;
      else ((bf16*)out)[oi] = __float2bfloat16(a);
    }
  }
}

extern "C" void kernel_launch(void* const* d_in, const int* in_sizes, int n_in,
                              void* d_out, int out_size, void* d_ws, size_t ws_size,
                              hipStream_t stream) {
  float* ws = (float*)d_ws;

  Ptrs pt;
  const int map[23] = {0, 1, 2, 3, 4, 5, 6, 7, 8, 10, 11, 12, 13, 14, 15, 16, 17,
                       18, 19, 20, 21, 22, 23};
  for (int j = 0; j < 23; j++) pt.p[j] = d_in[map[j]];

  k_convert<<<dim3((END_IN + 255) / 256), 256, 0, stream>>>(pt, d_in[2], ws);
  k_inproj<<<dim3(LSEQ / 16, 2), 256, 0, stream>>>(ws);
  k_conv<<<dim3(DI, 2), 256, 0, stream>>>(ws);
  k_xdbl<<<dim3(LSEQ / 64, NK), 256, 0, stream>>>(ws);
  k_scanA<<<dim3(NCHUNK, NK, 2), 128, 0, stream>>>(ws);
  k_comb<<<dim3(CHTOT / 256), 256, 0, stream>>>(ws);
  k_scanB<<<dim3(NCHUNK, NK, 2), 128, 0, stream>>>(ws);
  k_post<<<dim3(LSEQ / 32, 2), 256, 0, stream>>>(ws, d_in[2], d_out);
}

// Round 8
// 228.296 us; speedup vs baseline: 1.0431x; 1.0431x over previous
//
#include <hip/hip_runtime.h>
#include <hip/hip_bf16.h>
#include <math.h>

typedef __hip_bfloat16 bf16;

// ---------------- problem constants ----------------
#define LSEQ 4096
#define DI 128
#define NSTATE 16
#define NK 4
#define NCHUNK 128
#define CLEN 32
#define CHTOT 16384   // 2 scans * 4 k * 128 d * 16 n

// ---------------- fp32 input staging (packed, converted once per call) ----------------
#define IN_X0    0
#define IN_X1    262144
#define IN_IPW0  524288
#define IN_IPW1  540672
#define IN_CW0   557056
#define IN_CB0   558208
#define IN_CW1   558336
#define IN_CB1   559488
#define IN_XPW0  559616
#define IN_DTW0  578048
#define IN_DTW1  580096
#define IN_DTB0  582144
#define IN_DTB1  582656
#define IN_AL0   583168
#define IN_AL1   591360
#define IN_DS0   599552
#define IN_DS1   600064
#define IN_G0    600576
#define IN_B0    600704
#define IN_G1    600832
#define IN_B1    600960
#define IN_WO0   601088
#define IN_WO1   609280
#define END_IN   617472

// ---------------- intermediate buffers ----------------
#define OFF_XC0  END_IN                     // conv out branch0, [d][l] (row-major pixels)
#define OFF_XC1  (OFF_XC0 + DI*LSEQ)
#define OFF_XT0  (OFF_XC1 + DI*LSEQ)        // transposed plane, [d][w*64+h]
#define OFF_XT1  (OFF_XT0 + DI*LSEQ)
#define OFF_SZ0  (OFF_XT1 + DI*LSEQ)        // silu(z), [l][d]
#define OFF_SZ1  (OFF_SZ0 + LSEQ*DI)
#define OFF_XDBL (OFF_SZ1 + LSEQ*DI)        // [k][36][l]: rows 0-3 dtr, 4-19 B, 20-35 C
#define OFF_CHP  (OFF_XDBL + NK*36*LSEQ)    // [chunk][chain]; after k_comb holds h-init
#define OFF_CHS  (OFF_CHP + NCHUNK*CHTOT)
#define OFF_OY   (OFF_CHS + NCHUNK*CHTOT)   // per-direction scan out, [s][k][l][d]
#define WS_FLOATS (OFF_OY + 2*NK*LSEQ*DI)

__device__ __forceinline__ float softplus_f(float x) {
  return x > 20.f ? x : __logf(1.f + __expf(x));
}
__device__ __forceinline__ float silu_f(float x) {
  return x / (1.f + __expf(-x));
}
// inline dtype probe: wave 0 samples even bf16 indices of in_proj0_w.
// fp32-backed buffer -> even bf16 halves have random exponents -> many |v|>4/NaN.
__device__ __forceinline__ int probe_f32(const void* probe, int t, int* sh) {
  if (t < 64) {
    int idx = 2 * ((t * 127) & 4095);
    float v = __bfloat162float(((const bf16*)probe)[idx]);
    int weird = (!(v == v)) || (fabsf(v) > 4.0f);
    unsigned long long m = __ballot(weird);
    if (t == 0) *sh = (__popcll(m) >= 8) ? 1 : 0;
  }
  __syncthreads();
  return *sh;
}

// ---------------- K0: convert inputs to fp32 staging ----------------
struct Ptrs { const void* p[23]; };
__constant__ const int g_cnt[23] = {262144, 262144, 16384, 16384, 1152, 128, 1152, 128,
                                    18432, 2048, 2048, 512, 512, 8192, 8192, 512, 512,
                                    128, 128, 128, 128, 8192, 8192};
__constant__ const int g_dst[23] = {IN_X0, IN_X1, IN_IPW0, IN_IPW1, IN_CW0, IN_CB0,
                                    IN_CW1, IN_CB1, IN_XPW0, IN_DTW0, IN_DTW1, IN_DTB0,
                                    IN_DTB1, IN_AL0, IN_AL1, IN_DS0, IN_DS1, IN_G0,
                                    IN_B0, IN_G1, IN_B1, IN_WO0, IN_WO1};
__global__ __launch_bounds__(256) void k_convert(Ptrs pt, const void* probe,
                                                 float* __restrict__ ws) {
  __shared__ int sf32;
  int t = threadIdx.x;
  int f32 = probe_f32(probe, t, &sf32);
  int gid = blockIdx.x * 256 + t;
  if (gid < END_IN) {
    int j = 0;
#pragma unroll
    for (int q = 0; q < 22; q++)
      if (gid >= g_dst[q] + g_cnt[q]) j = q + 1;
    int off = gid - g_dst[j];
    float v;
    if (f32) v = ((const float*)pt.p[j])[off];
    else v = __bfloat162float(((const bf16*)pt.p[j])[off]);
    ws[gid] = v;
  }
}

// ---------------- K1: in_proj (x @ W^T), split xi / silu(z) ----------------
// x-tile addresses are wave-uniform -> compiler scalarizes to s_load (no LDS).
__global__ __launch_bounds__(256) void k_inproj(float* __restrict__ ws) {
  int b = blockIdx.y;
  const float* __restrict__ x = ws + (b ? IN_X1 : IN_X0);
  const float* __restrict__ w = ws + (b ? IN_IPW1 : IN_IPW0);
  float* xi = ws + (b ? OFF_XC1 : OFF_XC0);
  float* sz = ws + (b ? OFF_SZ1 : OFF_SZ0);
  int l0 = blockIdx.x * 16;
  int j = threadIdx.x;  // output channel 0..255
  float wr[64];
#pragma unroll
  for (int c = 0; c < 64; c++) wr[c] = w[j * 64 + c];
  float acc[16];
#pragma unroll
  for (int p = 0; p < 16; p++) acc[p] = 0.f;
#pragma unroll 4
  for (int p = 0; p < 16; p++) {
    const float* xr = x + (l0 + p) * 64;  // uniform -> scalar loads
#pragma unroll
    for (int c = 0; c < 64; c++) acc[p] += xr[c] * wr[c];
  }
  if (j < 128) {
#pragma unroll
    for (int p = 0; p < 16; p++) xi[j * LSEQ + l0 + p] = acc[p];
  } else {
    int d = j - 128;
#pragma unroll
    for (int p = 0; p < 16; p++) sz[(l0 + p) * 128 + d] = silu_f(acc[p]);
  }
}

// ---------------- K2: depthwise 3x3 conv + bias + SiLU; emit xc and transposed xcT ----------------
__global__ __launch_bounds__(256) void k_conv(float* __restrict__ ws) {
  int b = blockIdx.y;
  int d = blockIdx.x;
  const float* cw = ws + (b ? IN_CW1 : IN_CW0) + d * 9;
  float bias = (ws + (b ? IN_CB1 : IN_CB0))[d];
  float* xp = ws + (b ? OFF_XC1 : OFF_XC0) + d * LSEQ;
  float* xt = ws + (b ? OFF_XT1 : OFF_XT0) + d * LSEQ;
  float wreg[9];
#pragma unroll
  for (int i = 0; i < 9; i++) wreg[i] = cw[i];
  __shared__ float pl[64][64];
  __shared__ float po[64][65];
  for (int i = threadIdx.x; i < 4096; i += 256) pl[i >> 6][i & 63] = xp[i];
  __syncthreads();
  for (int i = threadIdx.x; i < 4096; i += 256) {
    int h = i >> 6, w = i & 63;
    float a = bias;
#pragma unroll
    for (int kh = 0; kh < 3; kh++) {
      int hh = h + kh - 1;
      if (hh < 0 || hh > 63) continue;
#pragma unroll
      for (int kw = 0; kw < 3; kw++) {
        int ww = w + kw - 1;
        if (ww < 0 || ww > 63) continue;
        a += pl[hh][ww] * wreg[kh * 3 + kw];
      }
    }
    float r = silu_f(a);
    xp[i] = r;
    po[w][h] = r;  // transposed stash
  }
  __syncthreads();
  for (int i = threadIdx.x; i < 4096; i += 256) xt[i] = po[i >> 6][i & 63];
}

// ---------------- K3: x_dbl[k,c,l] = sum_d xs0[k,d,l] * W0[k,c,d] ----------------
// wave = 9-c quarter (wave-uniform W -> s_load); lanes = 64 l; float4 LDS x reads.
__global__ __launch_bounds__(256) void k_xdbl(float* __restrict__ ws) {
  int k = blockIdx.y;
  int l0 = blockIdx.x * 64;
  int t = threadIdx.x;
  int lane = t & 63;
  int grp = t >> 6;  // wave id = c-quarter
  __shared__ __align__(16) float xtile[64 * 132];
  const float* pk = ws + ((k & 1) ? OFF_XT0 : OFF_XC0);  // branch0 planes
  int rev = (k >= 2);
  for (int i = t; i < 8192; i += 256) {
    int d = i >> 6, ll = i & 63;
    int idx = rev ? (4095 - (l0 + ll)) : (l0 + ll);
    xtile[ll * 132 + d] = pk[d * LSEQ + idx];
  }
  __syncthreads();
  const float* __restrict__ xpw = ws + IN_XPW0 + k * 4608;
  float acc[9];
#pragma unroll
  for (int i = 0; i < 9; i++) acc[i] = 0.f;
  for (int q = 0; q < 32; q++) {
    float4 x4 = *(const float4*)&xtile[lane * 132 + 4 * q];
#pragma unroll
    for (int i = 0; i < 9; i++) {
      int c = grp * 9 + i;
      float4 w4 = *(const float4*)&xpw[c * 128 + 4 * q];  // wave-uniform -> s_load
      acc[i] += x4.x * w4.x + x4.y * w4.y + x4.z * w4.z + x4.w * w4.w;
    }
  }
  float* xd = ws + OFF_XDBL + k * 36 * LSEQ;
#pragma unroll
  for (int i = 0; i < 9; i++) xd[(grp * 9 + i) * LSEQ + l0 + lane] = acc[i];
}

// ---------------- scan kernels ----------------
// thread owns a (s,k,d) chain with 16 n-states in registers.
// cross-wiring: s=0 scans xs0 with dt1/A1/D1 params; s=1 scans xs1 with dt0/A0/D0.
// Fast path: A_logs = log(1..16) => A[n] = (n+1)*A[0]  =>  exp(de*A[n]) = e1^(n+1).

// ---------------- K4a: scan pass 1 — per-chunk (P, S) ----------------
__global__ __launch_bounds__(128, 2) void k_scanA(float* __restrict__ ws) {
  int s = blockIdx.z, k = blockIdx.y, c = blockIdx.x;
  int d = threadIdx.x;  // 0..127
  const float* xd_dt = ws + OFF_XDBL + k * 36 * LSEQ;
  const float* Bb = ws + OFF_XDBL + (k * 36 + 4) * LSEQ;
  const float* alog = ws + (s ? IN_AL0 : IN_AL1);
  const float* dtw = ws + (s ? IN_DTW0 : IN_DTW1);
  const float* dtb = ws + (s ? IN_DTB0 : IN_DTB1);
  const float* uplane = ws + ((s ? OFF_XC1 : OFF_XC0) + ((k & 1) ? 2 * DI * LSEQ : 0)) + d * LSEQ;
  int rev = (k >= 2);
  float A[NSTATE];
#pragma unroll
  for (int n = 0; n < NSTATE; n++) A[n] = -__expf(alog[(k * DI + d) * NSTATE + n]);
  bool fast = true;
#pragma unroll
  for (int n = 1; n < NSTATE; n++)
    fast = fast && (fabsf(A[n] - (float)(n + 1) * A[0]) <= 1e-3f * fabsf(A[n]));
  float4 wrv = *(const float4*)&dtw[(k * DI + d) * 4];
  float dbias = dtb[k * DI + d];
  float h[NSTATE];
#pragma unroll
  for (int n = 0; n < NSTATE; n++) h[n] = 0.f;
  float sde = 0.f;
  __shared__ float dtr_s[4][16];
  __shared__ __align__(16) float Bt[16 * 20];  // row stride 20: conflict-light, 16B-aligned
  int l0 = c * CLEN;
  for (int tile = 0; tile < CLEN / 16; tile++) {
    int l0t = l0 + tile * 16;
    __syncthreads();
    if (d < 64) dtr_s[d >> 4][d & 15] = xd_dt[(d >> 4) * LSEQ + l0t + (d & 15)];
#pragma unroll
    for (int q = 0; q < 2; q++) {
      int i = d + q * 128;
      int n = i >> 4, j = i & 15;
      Bt[j * 20 + n] = Bb[n * LSEQ + l0t + j];
    }
    __syncthreads();
    float de[16];
#pragma unroll
    for (int j = 0; j < 16; j++) {
      de[j] = softplus_f(dtr_s[0][j] * wrv.x + dtr_s[1][j] * wrv.y +
                         dtr_s[2][j] * wrv.z + dtr_s[3][j] * wrv.w + dbias);
      sde += de[j];
    }
    int boff = rev ? (4080 - l0t) : l0t;
    float4 q0 = *(const float4*)&uplane[boff];
    float4 q1 = *(const float4*)&uplane[boff + 4];
    float4 q2 = *(const float4*)&uplane[boff + 8];
    float4 q3 = *(const float4*)&uplane[boff + 12];
    float uu[16] = {q0.x, q0.y, q0.z, q0.w, q1.x, q1.y, q1.z, q1.w,
                    q2.x, q2.y, q2.z, q2.w, q3.x, q3.y, q3.z, q3.w};
#pragma unroll
    for (int j = 0; j < 16; j++) {
      float u = rev ? uu[15 - j] : uu[j];
      float duj = de[j] * u;
      float4 b0 = *(const float4*)&Bt[j * 20 + 0];
      float4 b1 = *(const float4*)&Bt[j * 20 + 4];
      float4 b2 = *(const float4*)&Bt[j * 20 + 8];
      float4 b3 = *(const float4*)&Bt[j * 20 + 12];
      float bv[16] = {b0.x, b0.y, b0.z, b0.w, b1.x, b1.y, b1.z, b1.w,
                      b2.x, b2.y, b2.z, b2.w, b3.x, b3.y, b3.z, b3.w};
      if (fast) {
        float e1 = __expf(de[j] * A[0]);
        float p = e1;
#pragma unroll
        for (int n = 0; n < NSTATE; n++) {
          h[n] = p * h[n] + duj * bv[n];
          p *= e1;
        }
      } else {
#pragma unroll
        for (int n = 0; n < NSTATE; n++) {
          float da = __expf(de[j] * A[n]);
          h[n] = da * h[n] + duj * bv[n];
        }
      }
    }
  }
  int chainb = ((s * 4 + k) * DI + d) * NSTATE;
  float* Pp = ws + OFF_CHP + c * CHTOT + chainb;
  float* Sp = ws + OFF_CHS + c * CHTOT + chainb;
#pragma unroll
  for (int q = 0; q < 4; q++) {
    ((float4*)Pp)[q] = make_float4(__expf(A[4 * q] * sde), __expf(A[4 * q + 1] * sde),
                                   __expf(A[4 * q + 2] * sde), __expf(A[4 * q + 3] * sde));
    ((float4*)Sp)[q] = make_float4(h[4 * q], h[4 * q + 1], h[4 * q + 2], h[4 * q + 3]);
  }
}

// ---------------- K4b: combine chunk summaries; CHP becomes h-init in place ----------------
__global__ __launch_bounds__(256) void k_comb(float* __restrict__ ws) {
  int chain = blockIdx.x * 256 + threadIdx.x;
  float* P = ws + OFF_CHP + chain;
  float* S = ws + OFF_CHS + chain;
  float h = 0.f;
  for (int g = 0; g < NCHUNK; g += 8) {
    float p[8], sv[8];
#pragma unroll
    for (int i = 0; i < 8; i++) {
      p[i] = P[(g + i) * CHTOT];
      sv[i] = S[(g + i) * CHTOT];
    }
#pragma unroll
    for (int i = 0; i < 8; i++) {
      P[(g + i) * CHTOT] = h;
      h = p[i] * h + sv[i];
    }
  }
}

// ---------------- K4c: scan pass 2 — recompute with init, store y+u*D per direction ----------------
__global__ __launch_bounds__(128, 2) void k_scanB(float* __restrict__ ws) {
  int s = blockIdx.z, k = blockIdx.y, c = blockIdx.x;
  int d = threadIdx.x;
  const float* xd_dt = ws + OFF_XDBL + k * 36 * LSEQ;
  const float* Bb = ws + OFF_XDBL + (k * 36 + 4) * LSEQ;
  const float* Cb = ws + OFF_XDBL + (k * 36 + 20) * LSEQ;
  const float* alog = ws + (s ? IN_AL0 : IN_AL1);
  const float* dtw = ws + (s ? IN_DTW0 : IN_DTW1);
  const float* dtb = ws + (s ? IN_DTB0 : IN_DTB1);
  const float* Dvec = ws + (s ? IN_DS0 : IN_DS1);
  const float* uplane = ws + ((s ? OFF_XC1 : OFF_XC0) + ((k & 1) ? 2 * DI * LSEQ : 0)) + d * LSEQ;
  float* oyb = ws + OFF_OY + (s * NK + k) * (LSEQ * DI);
  int rev = (k >= 2);
  float A[NSTATE];
#pragma unroll
  for (int n = 0; n < NSTATE; n++) A[n] = -__expf(alog[(k * DI + d) * NSTATE + n]);
  bool fast = true;
#pragma unroll
  for (int n = 1; n < NSTATE; n++)
    fast = fast && (fabsf(A[n] - (float)(n + 1) * A[0]) <= 1e-3f * fabsf(A[n]));
  float4 wrv = *(const float4*)&dtw[(k * DI + d) * 4];
  float dbias = dtb[k * DI + d];
  float Dv = Dvec[k * DI + d];
  int chainb = ((s * 4 + k) * DI + d) * NSTATE;
  const float* Hp = ws + OFF_CHP + c * CHTOT + chainb;
  float h[NSTATE];
#pragma unroll
  for (int q = 0; q < 4; q++) {
    float4 hv = ((const float4*)Hp)[q];
    h[4 * q] = hv.x; h[4 * q + 1] = hv.y; h[4 * q + 2] = hv.z; h[4 * q + 3] = hv.w;
  }
  __shared__ float dtr_s[4][16];
  __shared__ __align__(16) float Bt[16 * 20];
  __shared__ __align__(16) float Ct[16 * 20];
  int l0 = c * CLEN;
  for (int tile = 0; tile < CLEN / 16; tile++) {
    int l0t = l0 + tile * 16;
    __syncthreads();
    if (d < 64) dtr_s[d >> 4][d & 15] = xd_dt[(d >> 4) * LSEQ + l0t + (d & 15)];
#pragma unroll
    for (int q = 0; q < 2; q++) {
      int i = d + q * 128;
      int n = i >> 4, j = i & 15;
      Bt[j * 20 + n] = Bb[n * LSEQ + l0t + j];
      Ct[j * 20 + n] = Cb[n * LSEQ + l0t + j];
    }
    __syncthreads();
    float de[16];
#pragma unroll
    for (int j = 0; j < 16; j++) {
      de[j] = softplus_f(dtr_s[0][j] * wrv.x + dtr_s[1][j] * wrv.y +
                         dtr_s[2][j] * wrv.z + dtr_s[3][j] * wrv.w + dbias);
    }
    int boff = rev ? (4080 - l0t) : l0t;
    float4 q0 = *(const float4*)&uplane[boff];
    float4 q1 = *(const float4*)&uplane[boff + 4];
    float4 q2 = *(const float4*)&uplane[boff + 8];
    float4 q3 = *(const float4*)&uplane[boff + 12];
    float uu[16] = {q0.x, q0.y, q0.z, q0.w, q1.x, q1.y, q1.z, q1.w,
                    q2.x, q2.y, q2.z, q2.w, q3.x, q3.y, q3.z, q3.w};
#pragma unroll
    for (int j = 0; j < 16; j++) {
      float u = rev ? uu[15 - j] : uu[j];
      float duj = de[j] * u;
      float4 b0 = *(const float4*)&Bt[j * 20 + 0];
      float4 b1 = *(const float4*)&Bt[j * 20 + 4];
      float4 b2 = *(const float4*)&Bt[j * 20 + 8];
      float4 b3 = *(const float4*)&Bt[j * 20 + 12];
      float bv[16] = {b0.x, b0.y, b0.z, b0.w, b1.x, b1.y, b1.z, b1.w,
                      b2.x, b2.y, b2.z, b2.w, b3.x, b3.y, b3.z, b3.w};
      float4 c0 = *(const float4*)&Ct[j * 20 + 0];
      float4 c1 = *(const float4*)&Ct[j * 20 + 4];
      float4 c2 = *(const float4*)&Ct[j * 20 + 8];
      float4 c3 = *(const float4*)&Ct[j * 20 + 12];
      float cv[16] = {c0.x, c0.y, c0.z, c0.w, c1.x, c1.y, c1.z, c1.w,
                      c2.x, c2.y, c2.z, c2.w, c3.x, c3.y, c3.z, c3.w};
      float y = 0.f;
      if (fast) {
        float e1 = __expf(de[j] * A[0]);
        float p = e1;
#pragma unroll
        for (int n = 0; n < NSTATE; n++) {
          h[n] = p * h[n] + duj * bv[n];
          y += h[n] * cv[n];
          p *= e1;
        }
      } else {
#pragma unroll
        for (int n = 0; n < NSTATE; n++) {
          float da = __expf(de[j] * A[n]);
          h[n] = da * h[n] + duj * bv[n];
          y += h[n] * cv[n];
        }
      }
      y += u * Dv;
      oyb[(l0t + j) * DI + d] = y;  // coalesced store, no atomics
    }
  }
}

// ---------------- K5: 4-dir gather + LayerNorm + gate + out_proj (restructured) ----------------
__global__ __launch_bounds__(256) void k_post(const float* __restrict__ ws,
                                              const void* probe,
                                              void* __restrict__ out) {
  int b = blockIdx.y;
  __shared__ int sf32;
  int t = threadIdx.x;
  int in_f32 = probe_f32(probe, t, &sf32);
  const float* oy = ws + OFF_OY + b * (NK * LSEQ * DI);
  const float* sz = ws + (b ? OFF_SZ1 : OFF_SZ0);
  const float* g = ws + (b ? IN_G1 : IN_G0);
  const float* be = ws + (b ? IN_B1 : IN_B0);
  const float* wo = ws + (b ? IN_WO1 : IN_WO0);
  __shared__ __align__(16) float yl[16 * 132];
  __shared__ float wl[64 * 129];
  // stage wo (read in phase B after the barrier)
  for (int i = t; i < 8192; i += 256) wl[(i >> 7) * 129 + (i & 127)] = wo[i];
  // ---- phase A: per-wave LN+gate, no barriers ----
  int wv = t >> 6, lane = t & 63;
  int l0 = blockIdx.x * 16;
  float g1 = g[lane], g2 = g[lane + 64];
  float be1 = be[lane], be2 = be[lane + 64];
#pragma unroll
  for (int i = 0; i < 4; i++) {
    int r = wv + 4 * i;
    int l = l0 + r;
    int lt = ((l & 63) << 6) | (l >> 6);
    float v1 = oy[(0 * LSEQ + l) * DI + lane] + oy[(1 * LSEQ + lt) * DI + lane] +
               oy[(2 * LSEQ + (4095 - l)) * DI + lane] + oy[(3 * LSEQ + (4095 - lt)) * DI + lane];
    float v2 = oy[(0 * LSEQ + l) * DI + lane + 64] + oy[(1 * LSEQ + lt) * DI + lane + 64] +
               oy[(2 * LSEQ + (4095 - l)) * DI + lane + 64] +
               oy[(3 * LSEQ + (4095 - lt)) * DI + lane + 64];
    float s1 = v1 + v2, s2 = v1 * v1 + v2 * v2;
#pragma unroll
    for (int m = 1; m < 64; m <<= 1) {
      s1 += __shfl_xor(s1, m);
      s2 += __shfl_xor(s2, m);
    }
    float mean = s1 * (1.f / 128.f);
    float var = s2 * (1.f / 128.f) - mean * mean;
    float inv = rsqrtf(var + 1e-5f);
    float ya1 = ((v1 - mean) * inv * g1 + be1) * sz[l * 128 + lane];
    float ya2 = ((v2 - mean) * inv * g2 + be2) * sz[l * 128 + lane + 64];
    yl[r * 132 + lane] = ya1;
    yl[r * 132 + lane + 64] = ya2;
  }
  __syncthreads();
  // ---- phase B: out GEMV, all 256 threads ----
  int m = t & 63, rg = t >> 6;
  float acc0 = 0.f, acc1 = 0.f, acc2 = 0.f, acc3 = 0.f;
  for (int q = 0; q < 32; q++) {
    float w0 = wl[m * 129 + 4 * q], w1 = wl[m * 129 + 4 * q + 1];
    float w2 = wl[m * 129 + 4 * q + 2], w3 = wl[m * 129 + 4 * q + 3];
    float4 y0 = *(const float4*)&yl[(rg + 0) * 132 + 4 * q];
    float4 y1 = *(const float4*)&yl[(rg + 4) * 132 + 4 * q];
    float4 y2 = *(const float4*)&yl[(rg + 8) * 132 + 4 * q];
    float4 y3 = *(const float4*)&yl[(rg + 12) * 132 + 4 * q];
    acc0 += y0.x * w0 + y0.y * w1 + y0.z * w2 + y0.w * w3;
    acc1 += y1.x * w0 + y1.y * w1 + y1.z * w2 + y1.w * w3;
    acc2 += y2.x * w0 + y2.y * w1 + y2.z * w2 + y2.w * w3;
    acc3 += y3.x * w0 + y3.y * w1 + y3.z * w2 + y3.w * w3;
  }
  float accs[4] = {acc0, acc1, acc2, acc3};
#pragma unroll
  for (int i = 0; i < 4; i++) {
    int l = l0 + rg + 4 * i;
    int oi = b * (LSEQ * 64) + l * 64 + m;
    if (in_f32) ((float*)out)[oi] = accs[i];
    else ((bf16*)out)[oi] = __float2bfloat16(accs[i]);
  }
}

extern "C" void kernel_launch(void* const* d_in, const int* in_sizes, int n_in,
                              void* d_out, int out_size, void* d_ws, size_t ws_size,
                              hipStream_t stream) {
  float* ws = (float*)d_ws;

  Ptrs pt;
  const int map[23] = {0, 1, 2, 3, 4, 5, 6, 7, 8, 10, 11, 12, 13, 14, 15, 16, 17,
                       18, 19, 20, 21, 22, 23};
  for (int j = 0; j < 23; j++) pt.p[j] = d_in[map[j]];

  k_convert<<<dim3((END_IN + 255) / 256), 256, 0, stream>>>(pt, d_in[2], ws);
  k_inproj<<<dim3(LSEQ / 16, 2), 256, 0, stream>>>(ws);
  k_conv<<<dim3(DI, 2), 256, 0, stream>>>(ws);
  k_xdbl<<<dim3(LSEQ / 64, NK), 256, 0, stream>>>(ws);
  k_scanA<<<dim3(NCHUNK, NK, 2), 128, 0, stream>>>(ws);
  k_comb<<<dim3(CHTOT / 256), 256, 0, stream>>>(ws);
  k_scanB<<<dim3(NCHUNK, NK, 2), 128, 0, stream>>>(ws);
  k_post<<<dim3(LSEQ / 16, 2), 256, 0, stream>>>(ws, d_in[2], d_out);
}